// Round 1
// baseline (2396.674 us; speedup 1.0000x reference)
//
#include <hip/hip_runtime.h>
#include <math.h>

typedef unsigned short u16;
typedef unsigned short us8 __attribute__((ext_vector_type(8)));

#define S3 884736L
#define MD3 13824L
#define NCH 56623104.0
#define NSP 884736.0

// ---- workspace layout (bytes) ----
#define A_CF   0L          // float Cf[24*96]   basis [k][n]
#define A_CT   9216L       // float Ct[96*24]   basis [n][k] (transposed)
#define A_ST   18432L      // double stats[16]: 0,1=gnm 2,3=gn0 4,5=gn1 6,7=gno 8,9=gnc
#define A_FLAG 18560L      // int: 1 = inputs are bf16, 0 = f32
#define A_W    18688L      // float[19200] converted small weights
#define A_Y    95488L      // bf16 y   [64][96^3]   mapping output (pre-GN)
#define A_T1   113341696L  // bf16 t1  [64][96][96][24]  (reused as o2)
#define A_T2   141653248L  // bf16 t2  [64][96][24][24]  (reused as o1)
#define A_XC   148731136L  // f32 xc   [64][24^3]
#define A_S0   152270080L  // f32 s0   [64][24^3]
#define A_S1   155809024L  // f32 s1   [64][24^3]
#define A_U    159347968L  // bf16 u   [64][96^3]   idht output (pre-GN)
// total = 272,594,176 bytes

// W layout (floats): Wm@0(2048) bm@2048 gnm_w@2112 gnm_b@2176 cw0@2240(4096)
// gn0_w@6336 gn0_b@6400 cw1@6464(4096) gn1_w@10560 gn1_b@10624 gno_w@10688
// gno_b@10752 Wc@10816(8192) bc@19008 gnc_w@19072 gnc_b@19136

__device__ __forceinline__ float b2f(u16 h){
  unsigned int u = ((unsigned int)h) << 16; float f;
  __builtin_memcpy(&f, &u, 4); return f;
}
__device__ __forceinline__ u16 f2b(float x){
  unsigned int u; __builtin_memcpy(&u, &x, 4);
  u = (u + 0x7FFFu + ((u >> 16) & 1u)) >> 16;
  return (u16)u;
}
template<int BF> __device__ __forceinline__ float ldin(const void* p, long i){
  return BF ? b2f(((const u16*)p)[i]) : ((const float*)p)[i];
}
__device__ __forceinline__ void get_mr(const double* st, int idx, double cnt,
                                       float& mu, float& rs){
  double m = st[idx] / cnt;
  double v = st[idx + 1] / cnt - m * m;
  mu = (float)m;
  rs = (float)(1.0 / sqrt(v + 1e-5));
}
// block = 256 threads (4 waves) assumed
__device__ __forceinline__ void statReduce(float s, float q, double* d0, double* d1){
  #pragma unroll
  for (int off = 32; off > 0; off >>= 1){
    s += __shfl_down(s, off, 64);
    q += __shfl_down(q, off, 64);
  }
  __shared__ float red[8];
  int w = threadIdx.x >> 6;
  if ((threadIdx.x & 63) == 0){ red[w] = s; red[4 + w] = q; }
  __syncthreads();
  if (threadIdx.x == 0){
    atomicAdd(d0, (double)(red[0] + red[1] + red[2] + red[3]));
    atomicAdd(d1, (double)(red[4] + red[5] + red[6] + red[7]));
  }
}

// ---- k0a: zero stats, detect dtype, build cas basis tables ----
__global__ __launch_bounds__(256) void k_init(float* Cf, float* Ct, double* st,
                                              int* flag, const void* x){
  int t = threadIdx.x;
  if (t < 16) st[t] = 0.0;
  if (t == 0){
    const u16* u = (const u16*)x; int sane = 0;
    for (int i = 0; i < 256; i++){
      int ex = (u[i] >> 7) & 0xFF;
      if (ex == 0 || (ex >= 104 && ex <= 150)) sane++;
    }
    *flag = (sane >= 240) ? 1 : 0;  // bf16 memory: ~256 sane; f32 memory: ~152
  }
  for (int i = t; i < 2304; i += 256){
    int kk = i / 96, n = i - kk * 96;
    int k = kk < 12 ? kk : kk + 72;   // kept freqs {0..11, 84..95}
    int r = (k * n) % 96;
    double th = 6.283185307179586 * (double)r / 96.0;
    float v = (float)(cos(th) + sin(th));   // cas
    Cf[kk * 96 + n] = v;
    Ct[n * 24 + kk] = v;
  }
}

// ---- k0b: convert small weights to f32 in ws ----
struct Segs { const void* src[16]; int n[16]; int off[16]; };
__global__ __launch_bounds__(256) void k_conv(Segs sg, float* W, const int* flag){
  int b = blockIdx.x;
  int bf = *flag;
  const void* s = sg.src[b]; int n = sg.n[b]; float* d = W + sg.off[b];
  for (int i = threadIdx.x; i < n; i += blockDim.x)
    d[i] = bf ? b2f(((const u16*)s)[i]) : ((const float*)s)[i];
}

// ---- k1: mapping conv 32->64 + bias; store bf16 y; gnm stats ----
template<int BF> __device__ void map_body(const void* x, const float* __restrict__ W,
                                          u16* __restrict__ y, double* st){
  long v = (long)blockIdx.x * 256 + threadIdx.x;
  float acc[64];
  #pragma unroll
  for (int o = 0; o < 64; o++) acc[o] = W[2048 + o];
  for (int i = 0; i < 32; i++){
    float xv = ldin<BF>(x, (long)i * S3 + v);
    #pragma unroll
    for (int o = 0; o < 64; o++) acc[o] = fmaf(W[i * 64 + o], xv, acc[o]);
  }
  float s = 0, q = 0;
  #pragma unroll
  for (int o = 0; o < 64; o++){
    s += acc[o]; q = fmaf(acc[o], acc[o], q);
    y[(long)o * S3 + v] = f2b(acc[o]);
  }
  statReduce(s, q, st, st + 1);
}
__global__ __launch_bounds__(256) void k_map(const void* x, const float* W, u16* y,
                                             double* st, const int* flag){
  if (*flag) map_body<1>(x, W, y, st); else map_body<0>(x, W, y, st);
}

// ---- k2: GN_m + relu on the fly, DHT along z (96 -> 24 modes) ----
__global__ __launch_bounds__(256) void k_dhtz(const u16* __restrict__ y, u16* __restrict__ t1,
                                              const float* __restrict__ Ct,
                                              const float* __restrict__ W,
                                              const double* __restrict__ st){
  long r = (long)blockIdx.x * 256 + threadIdx.x;   // (c,x,y) row, 589824
  int c = (int)(r / 9216);
  float mu, rs; get_mr(st, 0, NCH, mu, rs);
  float a = rs * W[2112 + c];
  float bb = W[2176 + c] - mu * a;
  const u16* in = y + r * 96;
  float acc[24];
  #pragma unroll
  for (int k = 0; k < 24; k++) acc[k] = 0.f;
  for (int z0 = 0; z0 < 96; z0 += 8){
    us8 h = *(const us8*)(in + z0);
    #pragma unroll
    for (int j = 0; j < 8; j++){
      float v = fmaxf(fmaf(b2f(h[j]), a, bb), 0.f);
      const float* ct = Ct + (z0 + j) * 24;
      #pragma unroll
      for (int k = 0; k < 24; k++) acc[k] = fmaf(v, ct[k], acc[k]);
    }
  }
  u16* out = t1 + r * 24;
  #pragma unroll
  for (int g = 0; g < 3; g++){
    us8 o8;
    #pragma unroll
    for (int j = 0; j < 8; j++) o8[j] = f2b(acc[g * 8 + j]);
    *(us8*)(out + g * 8) = o8;
  }
}

// ---- k3: DHT along y ----
__global__ __launch_bounds__(256) void k_dhty(const u16* __restrict__ t1, u16* __restrict__ t2,
                                              const float* __restrict__ Ct){
  int t = blockIdx.x * 256 + threadIdx.x;   // 147456 = (c,x) * kk
  int kk = t % 24; int cx = t / 24;
  const u16* in = t1 + (long)cx * 2304 + kk;
  float acc[24];
  #pragma unroll
  for (int k = 0; k < 24; k++) acc[k] = 0.f;
  for (int yy = 0; yy < 96; yy++){
    float v = b2f(in[yy * 24]);
    const float* ct = Ct + yy * 24;
    #pragma unroll
    for (int ky = 0; ky < 24; ky++) acc[ky] = fmaf(v, ct[ky], acc[ky]);
  }
  u16* out = t2 + (long)cx * 576 + kk;
  #pragma unroll
  for (int ky = 0; ky < 24; ky++) out[ky * 24] = f2b(acc[ky]);
}

// ---- k4: DHT along x -> xc (f32) ----
__global__ __launch_bounds__(256) void k_dhtx(const u16* __restrict__ t2, float* __restrict__ xc,
                                              const float* __restrict__ Ct){
  int t = blockIdx.x * 256 + threadIdx.x;   // 36864 = c * (ky,kz)
  int kykk = t % 576; int c = t / 576;
  const u16* in = t2 + (long)c * 55296 + kykk;
  float acc[24];
  #pragma unroll
  for (int k = 0; k < 24; k++) acc[k] = 0.f;
  for (int xx = 0; xx < 96; xx++){
    float v = b2f(in[xx * 576]);
    const float* ct = Ct + xx * 24;
    #pragma unroll
    for (int kx = 0; kx < 24; kx++) acc[kx] = fmaf(v, ct[kx], acc[kx]);
  }
  float* out = xc + (long)c * 13824 + kykk;
  #pragma unroll
  for (int kx = 0; kx < 24; kx++) out[kx * 576] = acc[kx];
}

// ---- k5: spectral block: x1(per-mode 64x64) + x2(1x1 conv) + residual; stats ----
template<int BF> __device__ void spec_body(float* xin, const float* __restrict__ in,
    const void* __restrict__ sw, const float* __restrict__ W, int cwOff, int gwOff,
    int statIn, float* __restrict__ out, double* st, int statOut){
  int lane = threadIdx.x & 63, grp = threadIdx.x >> 6;
  long p = (long)blockIdx.x * 64 + lane;
  int o = blockIdx.y * 4 + grp;
  float mu = 0, rs = 0;
  if (statIn >= 0) get_mr(st, statIn, NSP, mu, rs);
  #pragma unroll
  for (int ii = 0; ii < 16; ii++){
    int i = grp + ii * 4;
    float v = in[i * MD3 + p];
    if (statIn >= 0){
      float a = rs * W[gwOff + i];
      v = fmaxf(fmaf(v, a, W[gwOff + 64 + i] - mu * a), 0.f);
    }
    xin[i * 64 + lane] = v;
  }
  __syncthreads();
  const float* cw = W + cwOff;
  float a1 = 0, a2 = 0;
  for (int i = 0; i < 64; i++){
    float xi = xin[i * 64 + lane];
    a1 = fmaf(ldin<BF>(sw, (long)(i * 64 + o) * MD3 + p), xi, a1);
    a2 = fmaf(cw[i * 64 + o], xi, a2);
  }
  float sv = a1 + a2 + xin[o * 64 + lane];
  out[o * MD3 + p] = sv;
  statReduce(sv, sv * sv, st + statOut, st + statOut + 1);
}
__global__ __launch_bounds__(256) void k_spec(const float* in, const void* sw, const float* W,
    int cwOff, int gwOff, int statIn, float* out, double* st, int statOut, const int* flag){
  __shared__ float xin[4096];
  if (*flag) spec_body<1>(xin, in, sw, W, cwOff, gwOff, statIn, out, st, statOut);
  else       spec_body<0>(xin, in, sw, W, cwOff, gwOff, statIn, out, st, statOut);
}

// ---- k6: GN1+relu on the fly, inverse along x (24 modes -> 96), scale 1/96 ----
__global__ __launch_bounds__(256) void k_invx(const float* __restrict__ s1, u16* __restrict__ o1,
                                              const float* __restrict__ Cf,
                                              const float* __restrict__ W,
                                              const double* __restrict__ st){
  int t = blockIdx.x * 256 + threadIdx.x;   // 36864
  int kykk = t % 576; int o = t / 576;
  float mu, rs; get_mr(st, 4, NSP, mu, rs);
  float a = rs * W[10560 + o];
  float bb = W[10624 + o] - mu * a;
  float xin[24];
  #pragma unroll
  for (int kx = 0; kx < 24; kx++)
    xin[kx] = fmaxf(fmaf(s1[(long)o * MD3 + kx * 576 + kykk], a, bb), 0.f);
  u16* out = o1 + (long)o * 55296 + kykk;
  const float sc = 1.f / 96.f;
  for (int x0 = 0; x0 < 96; x0 += 8){
    float acc[8];
    #pragma unroll
    for (int j = 0; j < 8; j++) acc[j] = 0.f;
    #pragma unroll
    for (int kx = 0; kx < 24; kx++){
      float f = xin[kx];
      const float* cf = Cf + kx * 96 + x0;
      #pragma unroll
      for (int j = 0; j < 8; j++) acc[j] = fmaf(f, cf[j], acc[j]);
    }
    #pragma unroll
    for (int j = 0; j < 8; j++) out[(x0 + j) * 576] = f2b(acc[j] * sc);
  }
}

// ---- k7: inverse along y ----
__global__ __launch_bounds__(256) void k_invy(const u16* __restrict__ o1, u16* __restrict__ o2,
                                              const float* __restrict__ Cf){
  int t = blockIdx.x * 256 + threadIdx.x;   // 147456
  int kz = t % 24; int xx = (t / 24) % 96; int o = t / 2304;
  const u16* in = o1 + (long)o * 55296 + xx * 576 + kz;
  float xin[24];
  #pragma unroll
  for (int ky = 0; ky < 24; ky++) xin[ky] = b2f(in[ky * 24]);
  u16* out = o2 + (long)o * 221184 + xx * 2304 + kz;
  const float sc = 1.f / 96.f;
  for (int y0 = 0; y0 < 96; y0 += 8){
    float acc[8];
    #pragma unroll
    for (int j = 0; j < 8; j++) acc[j] = 0.f;
    #pragma unroll
    for (int ky = 0; ky < 24; ky++){
      float f = xin[ky];
      const float* cf = Cf + ky * 96 + y0;
      #pragma unroll
      for (int j = 0; j < 8; j++) acc[j] = fmaf(f, cf[j], acc[j]);
    }
    #pragma unroll
    for (int j = 0; j < 8; j++) out[(y0 + j) * 24] = f2b(acc[j] * sc);
  }
}

// ---- k8: inverse along z -> u (bf16); gno stats ----
__global__ __launch_bounds__(256) void k_invz(const u16* __restrict__ o2, u16* __restrict__ u,
                                              const float* __restrict__ Cf, double* st){
  long r = (long)blockIdx.x * 256 + threadIdx.x;   // 589824 rows
  const u16* in = o2 + r * 24;
  us8 h0 = *(const us8*)(in), h1 = *(const us8*)(in + 8), h2 = *(const us8*)(in + 16);
  float xin[24];
  #pragma unroll
  for (int j = 0; j < 8; j++){ xin[j] = b2f(h0[j]); xin[8 + j] = b2f(h1[j]); xin[16 + j] = b2f(h2[j]); }
  u16* out = u + r * 96;
  float s = 0, q = 0;
  const float sc = 1.f / 96.f;
  for (int z0 = 0; z0 < 96; z0 += 8){
    float acc[8];
    #pragma unroll
    for (int j = 0; j < 8; j++) acc[j] = 0.f;
    #pragma unroll
    for (int kz = 0; kz < 24; kz++){
      float f = xin[kz];
      const float* cf = Cf + kz * 96 + z0;
      #pragma unroll
      for (int j = 0; j < 8; j++) acc[j] = fmaf(f, cf[j], acc[j]);
    }
    us8 o8;
    #pragma unroll
    for (int j = 0; j < 8; j++){
      float vv = acc[j] * sc;
      s += vv; q = fmaf(vv, vv, q);
      o8[j] = f2b(vv);
    }
    *(us8*)(out + z0) = o8;
  }
  statReduce(s, q, st + 6, st + 7);
}

// ---- k9: final concat-conv 128->64 (+bias); z to d_out; gnc stats ----
template<int OBF> __device__ void fin_body(const u16* __restrict__ u, const u16* __restrict__ y,
    const float* __restrict__ W, void* __restrict__ zout, double* st){
  long v = (long)blockIdx.x * 256 + threadIdx.x;
  float muo, rso, mum, rsm;
  get_mr(st, 6, NCH, muo, rso);
  get_mr(st, 0, NCH, mum, rsm);
  float acc[64];
  #pragma unroll
  for (int o = 0; o < 64; o++) acc[o] = W[19008 + o];
  for (int i = 0; i < 64; i++){
    float a = rso * W[10688 + i];
    float ui = fmaxf(fmaf(b2f(u[(long)i * S3 + v]), a, W[10752 + i] - muo * a), 0.f);
    const float* wr = W + 10816 + i * 64;
    #pragma unroll
    for (int o = 0; o < 64; o++) acc[o] = fmaf(wr[o], ui, acc[o]);
  }
  for (int i = 0; i < 64; i++){
    float a = rsm * W[2112 + i];
    float ti = fmaxf(fmaf(b2f(y[(long)i * S3 + v]), a, W[2176 + i] - mum * a), 0.f);
    const float* wr = W + 10816 + (64 + i) * 64;
    #pragma unroll
    for (int o = 0; o < 64; o++) acc[o] = fmaf(wr[o], ti, acc[o]);
  }
  float s = 0, q = 0;
  #pragma unroll
  for (int o = 0; o < 64; o++){
    s += acc[o]; q = fmaf(acc[o], acc[o], q);
    if (OBF) ((u16*)zout)[(long)o * S3 + v] = f2b(acc[o]);
    else     ((float*)zout)[(long)o * S3 + v] = acc[o];
  }
  statReduce(s, q, st + 8, st + 9);
}
__global__ __launch_bounds__(256) void k_fin(const u16* u, const u16* y, const float* W,
                                             void* z, double* st, const int* flag){
  if (*flag) fin_body<1>(u, y, W, z, st); else fin_body<0>(u, y, W, z, st);
}

// ---- k10: GN_c + relu in-place on d_out ----
template<int OBF> __device__ void norm_body(void* z, const float* __restrict__ W,
                                            const double* __restrict__ st){
  long idx = ((long)blockIdx.x * 256 + threadIdx.x) * 8;
  float mu, rs; get_mr(st, 8, NCH, mu, rs);
  int c = (int)(idx / S3);
  float a = rs * W[19072 + c];
  float bb = W[19136 + c] - mu * a;
  if (OBF){
    u16* p = (u16*)z + idx;
    us8 h = *(us8*)p, o8;
    #pragma unroll
    for (int j = 0; j < 8; j++) o8[j] = f2b(fmaxf(fmaf(b2f(h[j]), a, bb), 0.f));
    *(us8*)p = o8;
  } else {
    float* p = (float*)z + idx;
    float4 v0 = *(float4*)p, v1 = *(float4*)(p + 4);
    v0.x = fmaxf(fmaf(v0.x, a, bb), 0.f); v0.y = fmaxf(fmaf(v0.y, a, bb), 0.f);
    v0.z = fmaxf(fmaf(v0.z, a, bb), 0.f); v0.w = fmaxf(fmaf(v0.w, a, bb), 0.f);
    v1.x = fmaxf(fmaf(v1.x, a, bb), 0.f); v1.y = fmaxf(fmaf(v1.y, a, bb), 0.f);
    v1.z = fmaxf(fmaf(v1.z, a, bb), 0.f); v1.w = fmaxf(fmaf(v1.w, a, bb), 0.f);
    *(float4*)p = v0; *(float4*)(p + 4) = v1;
  }
}
__global__ __launch_bounds__(256) void k_norm(void* z, const float* W, const double* st,
                                              const int* flag){
  if (*flag) norm_body<1>(z, W, st); else norm_body<0>(z, W, st);
}

extern "C" void kernel_launch(void* const* d_in, const int* in_sizes, int n_in,
                              void* d_out, int out_size, void* d_ws, size_t ws_size,
                              hipStream_t stream){
  char* ws = (char*)d_ws;
  float*  Cf   = (float*)(ws + A_CF);
  float*  Ct   = (float*)(ws + A_CT);
  double* st   = (double*)(ws + A_ST);
  int*    flag = (int*)(ws + A_FLAG);
  float*  W    = (float*)(ws + A_W);
  u16*    y    = (u16*)(ws + A_Y);
  u16*    t1   = (u16*)(ws + A_T1);
  u16*    t2   = (u16*)(ws + A_T2);
  float*  xc   = (float*)(ws + A_XC);
  float*  s0   = (float*)(ws + A_S0);
  float*  s1   = (float*)(ws + A_S1);
  u16*    u    = (u16*)(ws + A_U);

  k_init<<<1, 256, 0, stream>>>(Cf, Ct, st, flag, d_in[0]);

  Segs sg;
  const int offs[16] = {0,2048,2112,2176,2240,6336,6400,6464,10560,10624,10688,10752,10816,19008,19072,19136};
  const int ns[16]   = {2048,64,64,64,4096,64,64,4096,64,64,64,64,8192,64,64,64};
  const int idxs[16] = {1,2,3,4,6,7,8,10,11,12,13,14,15,16,17,18};
  for (int i = 0; i < 16; i++){ sg.src[i] = d_in[idxs[i]]; sg.n[i] = ns[i]; sg.off[i] = offs[i]; }
  k_conv<<<16, 256, 0, stream>>>(sg, W, flag);

  k_map <<<3456, 256, 0, stream>>>(d_in[0], W, y, st, flag);
  k_dhtz<<<2304, 256, 0, stream>>>(y, t1, Ct, W, st);
  k_dhty<<<576,  256, 0, stream>>>(t1, t2, Ct);
  k_dhtx<<<144,  256, 0, stream>>>(t2, xc, Ct);

  // spectral block 0: raw xc in; gn0 stats out
  k_spec<<<dim3(216, 16), 256, 0, stream>>>(xc, d_in[5], W, 2240, 0, -1, s0, st, 2, flag);
  // spectral block 1: normalize s0 with gn0; gn1 stats out
  k_spec<<<dim3(216, 16), 256, 0, stream>>>(s0, d_in[9], W, 6464, 6336, 2, s1, st, 4, flag);

  k_invx<<<144,  256, 0, stream>>>(s1, t2, Cf, W, st);   // t2 reused as o1
  k_invy<<<576,  256, 0, stream>>>(t2, t1, Cf);          // t1 reused as o2
  k_invz<<<2304, 256, 0, stream>>>(t1, u, Cf, st);

  k_fin <<<3456, 256, 0, stream>>>(u, y, W, d_out, st, flag);
  k_norm<<<27648, 256, 0, stream>>>(d_out, W, st, flag);
}

// Round 2
// 2266.973 us; speedup vs baseline: 1.0572x; 1.0572x over previous
//
#include <hip/hip_runtime.h>
#include <math.h>

typedef unsigned short u16;
typedef unsigned short us8 __attribute__((ext_vector_type(8)));

#define S3 884736L
#define MD3 13824L
#define NCH 56623104.0
#define NSP 884736.0

// ---- workspace layout (bytes) ----
#define A_CF   0L          // float Cf[24*96]   basis [k][n]
#define A_CT   9216L       // float Ct[96*24]   basis [n][k] (transposed)
#define A_ST   18432L      // double stats[16]: 0,1=gnm 2,3=gn0 4,5=gn1 6,7=gno 8,9=gnc
#define A_FLAG 18560L      // int: 1 = inputs are bf16, 0 = f32
#define A_W    18688L      // float[19200] converted small weights
#define A_Y    95488L      // bf16 y   [64][96^3]   mapping output (pre-GN)
#define A_T1   113341696L  // bf16 t1  [64][96][96][24]  (reused as o2)
#define A_T2   141653248L  // bf16 t2  [64][96][24][24]  (reused as o1)
#define A_XC   148731136L  // f32 xc   [64][24^3]
#define A_S0   152270080L  // f32 s0   [64][24^3]
#define A_S1   155809024L  // f32 s1   [64][24^3]
#define A_U    159347968L  // bf16 u   [64][96^3]   idht output (pre-GN)
// total = 272,594,176 bytes

// W layout (floats): Wm@0(2048) bm@2048 gnm_w@2112 gnm_b@2176 cw0@2240(4096)
// gn0_w@6336 gn0_b@6400 cw1@6464(4096) gn1_w@10560 gn1_b@10624 gno_w@10688
// gno_b@10752 Wc@10816(8192) bc@19008 gnc_w@19072 gnc_b@19136

__device__ __forceinline__ float b2f(u16 h){
  unsigned int u = ((unsigned int)h) << 16; float f;
  __builtin_memcpy(&f, &u, 4); return f;
}
__device__ __forceinline__ u16 f2b(float x){
  unsigned int u; __builtin_memcpy(&u, &x, 4);
  u = (u + 0x7FFFu + ((u >> 16) & 1u)) >> 16;
  return (u16)u;
}
template<int BF> __device__ __forceinline__ float ldin(const void* p, long i){
  return BF ? b2f(((const u16*)p)[i]) : ((const float*)p)[i];
}
__device__ __forceinline__ void get_mr(const double* st, int idx, double cnt,
                                       float& mu, float& rs){
  double m = st[idx] / cnt;
  double v = st[idx + 1] / cnt - m * m;
  mu = (float)m;
  rs = (float)(1.0 / sqrt(v + 1e-5));
}
// block = 256 threads (4 waves) assumed
__device__ __forceinline__ void statReduce(float s, float q, double* d0, double* d1){
  #pragma unroll
  for (int off = 32; off > 0; off >>= 1){
    s += __shfl_down(s, off, 64);
    q += __shfl_down(q, off, 64);
  }
  __shared__ float red[8];
  int w = threadIdx.x >> 6;
  if ((threadIdx.x & 63) == 0){ red[w] = s; red[4 + w] = q; }
  __syncthreads();
  if (threadIdx.x == 0){
    atomicAdd(d0, (double)(red[0] + red[1] + red[2] + red[3]));
    atomicAdd(d1, (double)(red[4] + red[5] + red[6] + red[7]));
  }
}

// ---- k0a: zero stats, detect dtype, build cas basis tables ----
__global__ __launch_bounds__(256) void k_init(float* Cf, float* Ct, double* st,
                                              int* flag, const void* x){
  int t = threadIdx.x;
  if (t < 16) st[t] = 0.0;
  if (t == 0){
    const u16* u = (const u16*)x; int sane = 0;
    for (int i = 0; i < 256; i++){
      int ex = (u[i] >> 7) & 0xFF;
      if (ex == 0 || (ex >= 104 && ex <= 150)) sane++;
    }
    *flag = (sane >= 240) ? 1 : 0;
  }
  for (int i = t; i < 2304; i += 256){
    int kk = i / 96, n = i - kk * 96;
    int k = kk < 12 ? kk : kk + 72;   // kept freqs {0..11, 84..95}
    int r = (k * n) % 96;
    double th = 6.283185307179586 * (double)r / 96.0;
    float v = (float)(cos(th) + sin(th));   // cas
    Cf[kk * 96 + n] = v;
    Ct[n * 24 + kk] = v;
  }
}

// ---- k0b: convert small weights to f32 in ws ----
struct Segs { const void* src[16]; int n[16]; int off[16]; };
__global__ __launch_bounds__(256) void k_conv(Segs sg, float* W, const int* flag){
  int b = blockIdx.x;
  int bf = *flag;
  const void* s = sg.src[b]; int n = sg.n[b]; float* d = W + sg.off[b];
  for (int i = threadIdx.x; i < n; i += blockDim.x)
    d[i] = bf ? b2f(((const u16*)s)[i]) : ((const float*)s)[i];
}

// ---- k1: mapping conv 32->64 + bias; LDS-tiled; store bf16 y; gnm stats ----
// block = 64 voxels; thread = (voxel=lane, out-group=wave of 16 channels)
template<int BF> __device__ void map_body(float* xs, const void* x,
                                          const float* __restrict__ W,
                                          u16* __restrict__ y, double* st){
  long vb = (long)blockIdx.x * 64;
  int t = threadIdx.x;
  if (BF){
    int row = t >> 3, seg = t & 7;              // 32 rows x 8 threads x 8 elems
    const u16* src = (const u16*)x + (long)row * S3 + vb + seg * 8;
    us8 h = *(const us8*)src;
    #pragma unroll
    for (int j = 0; j < 8; j++) xs[row * 64 + seg * 8 + j] = b2f(h[j]);
  } else {
    int row = t >> 4, seg = t & 15;             // 16 rows/pass x 16 thr x 4 f32
    #pragma unroll
    for (int p = 0; p < 2; p++){
      const float* src = (const float*)x + (long)(row + 16 * p) * S3 + vb + seg * 4;
      float4 v4 = *(const float4*)src;
      *(float4*)&xs[(row + 16 * p) * 64 + seg * 4] = v4;
    }
  }
  __syncthreads();
  int lane = t & 63, g = t >> 6;
  int ob = g * 16;
  float acc[16];
  #pragma unroll
  for (int o = 0; o < 16; o++) acc[o] = W[2048 + ob + o];
  for (int i = 0; i < 32; i++){
    float xi = xs[i * 64 + lane];
    const float* wr = W + i * 64 + ob;
    #pragma unroll
    for (int o = 0; o < 16; o++) acc[o] = fmaf(wr[o], xi, acc[o]);
  }
  float s = 0, q = 0;
  #pragma unroll
  for (int o = 0; o < 16; o++){
    s += acc[o]; q = fmaf(acc[o], acc[o], q);
    y[(long)(ob + o) * S3 + vb + lane] = f2b(acc[o]);
  }
  statReduce(s, q, st, st + 1);
}
__global__ __launch_bounds__(256) void k_map(const void* x, const float* W, u16* y,
                                             double* st, const int* flag){
  __shared__ float xs[32 * 64];
  if (*flag) map_body<1>(xs, x, W, y, st); else map_body<0>(xs, x, W, y, st);
}

// ---- k2: GN_m + relu on the fly, DHT along z (96 -> 24 modes) ----
__global__ __launch_bounds__(256) void k_dhtz(const u16* __restrict__ y, u16* __restrict__ t1,
                                              const float* __restrict__ Ct,
                                              const float* __restrict__ W,
                                              const double* __restrict__ st){
  long r = (long)blockIdx.x * 256 + threadIdx.x;   // (c,x,y) row, 589824
  int c = (int)(r / 9216);
  float mu, rs; get_mr(st, 0, NCH, mu, rs);
  float a = rs * W[2112 + c];
  float bb = W[2176 + c] - mu * a;
  const u16* in = y + r * 96;
  float acc[24];
  #pragma unroll
  for (int k = 0; k < 24; k++) acc[k] = 0.f;
  for (int z0 = 0; z0 < 96; z0 += 8){
    us8 h = *(const us8*)(in + z0);
    #pragma unroll
    for (int j = 0; j < 8; j++){
      float v = fmaxf(fmaf(b2f(h[j]), a, bb), 0.f);
      const float* ct = Ct + (z0 + j) * 24;
      #pragma unroll
      for (int k = 0; k < 24; k++) acc[k] = fmaf(v, ct[k], acc[k]);
    }
  }
  u16* out = t1 + r * 24;
  #pragma unroll
  for (int g = 0; g < 3; g++){
    us8 o8;
    #pragma unroll
    for (int j = 0; j < 8; j++) o8[j] = f2b(acc[g * 8 + j]);
    *(us8*)(out + g * 8) = o8;
  }
}

// ---- k3: DHT along y ----
__global__ __launch_bounds__(256) void k_dhty(const u16* __restrict__ t1, u16* __restrict__ t2,
                                              const float* __restrict__ Ct){
  int t = blockIdx.x * 256 + threadIdx.x;   // 147456 = (c,x) * kk
  int kk = t % 24; int cx = t / 24;
  const u16* in = t1 + (long)cx * 2304 + kk;
  float acc[24];
  #pragma unroll
  for (int k = 0; k < 24; k++) acc[k] = 0.f;
  for (int yy = 0; yy < 96; yy++){
    float v = b2f(in[yy * 24]);
    const float* ct = Ct + yy * 24;
    #pragma unroll
    for (int ky = 0; ky < 24; ky++) acc[ky] = fmaf(v, ct[ky], acc[ky]);
  }
  u16* out = t2 + (long)cx * 576 + kk;
  #pragma unroll
  for (int ky = 0; ky < 24; ky++) out[ky * 24] = f2b(acc[ky]);
}

// ---- k4: DHT along x -> xc (f32) ----
__global__ __launch_bounds__(256) void k_dhtx(const u16* __restrict__ t2, float* __restrict__ xc,
                                              const float* __restrict__ Ct){
  int t = blockIdx.x * 256 + threadIdx.x;   // 36864 = c * (ky,kz)
  int kykk = t % 576; int c = t / 576;
  const u16* in = t2 + (long)c * 55296 + kykk;
  float acc[24];
  #pragma unroll
  for (int k = 0; k < 24; k++) acc[k] = 0.f;
  for (int xx = 0; xx < 96; xx++){
    float v = b2f(in[xx * 576]);
    const float* ct = Ct + xx * 24;
    #pragma unroll
    for (int kx = 0; kx < 24; kx++) acc[kx] = fmaf(v, ct[kx], acc[kx]);
  }
  float* out = xc + (long)c * 13824 + kykk;
  #pragma unroll
  for (int kx = 0; kx < 24; kx++) out[kx * 576] = acc[kx];
}

// ---- k5: spectral block: x1(per-mode 64x64) + x2(1x1 conv) + residual; stats ----
template<int BF> __device__ void spec_body(float* xin, const float* __restrict__ in,
    const void* __restrict__ sw, const float* __restrict__ W, int cwOff, int gwOff,
    int statIn, float* __restrict__ out, double* st, int statOut){
  int lane = threadIdx.x & 63, grp = threadIdx.x >> 6;
  long p = (long)blockIdx.x * 64 + lane;
  int o = blockIdx.y * 4 + grp;
  float mu = 0, rs = 0;
  if (statIn >= 0) get_mr(st, statIn, NSP, mu, rs);
  #pragma unroll
  for (int ii = 0; ii < 16; ii++){
    int i = grp + ii * 4;
    float v = in[i * MD3 + p];
    if (statIn >= 0){
      float a = rs * W[gwOff + i];
      v = fmaxf(fmaf(v, a, W[gwOff + 64 + i] - mu * a), 0.f);
    }
    xin[i * 64 + lane] = v;
  }
  __syncthreads();
  const float* cw = W + cwOff;
  float a1 = 0, a2 = 0;
  for (int i = 0; i < 64; i++){
    float xi = xin[i * 64 + lane];
    a1 = fmaf(ldin<BF>(sw, (long)(i * 64 + o) * MD3 + p), xi, a1);
    a2 = fmaf(cw[i * 64 + o], xi, a2);
  }
  float sv = a1 + a2 + xin[o * 64 + lane];
  out[o * MD3 + p] = sv;
  statReduce(sv, sv * sv, st + statOut, st + statOut + 1);
}
__global__ __launch_bounds__(256) void k_spec(const float* in, const void* sw, const float* W,
    int cwOff, int gwOff, int statIn, float* out, double* st, int statOut, const int* flag){
  __shared__ float xin[4096];
  if (*flag) spec_body<1>(xin, in, sw, W, cwOff, gwOff, statIn, out, st, statOut);
  else       spec_body<0>(xin, in, sw, W, cwOff, gwOff, statIn, out, st, statOut);
}

// ---- k6: GN1+relu on the fly, inverse along x (24 modes -> 96), scale 1/96 ----
__global__ __launch_bounds__(256) void k_invx(const float* __restrict__ s1, u16* __restrict__ o1,
                                              const float* __restrict__ Cf,
                                              const float* __restrict__ W,
                                              const double* __restrict__ st){
  int t = blockIdx.x * 256 + threadIdx.x;   // 36864
  int kykk = t % 576; int o = t / 576;
  float mu, rs; get_mr(st, 4, NSP, mu, rs);
  float a = rs * W[10560 + o];
  float bb = W[10624 + o] - mu * a;
  float xin[24];
  #pragma unroll
  for (int kx = 0; kx < 24; kx++)
    xin[kx] = fmaxf(fmaf(s1[(long)o * MD3 + kx * 576 + kykk], a, bb), 0.f);
  u16* out = o1 + (long)o * 55296 + kykk;
  const float sc = 1.f / 96.f;
  for (int x0 = 0; x0 < 96; x0 += 8){
    float acc[8];
    #pragma unroll
    for (int j = 0; j < 8; j++) acc[j] = 0.f;
    #pragma unroll
    for (int kx = 0; kx < 24; kx++){
      float f = xin[kx];
      const float* cf = Cf + kx * 96 + x0;
      #pragma unroll
      for (int j = 0; j < 8; j++) acc[j] = fmaf(f, cf[j], acc[j]);
    }
    #pragma unroll
    for (int j = 0; j < 8; j++) out[(x0 + j) * 576] = f2b(acc[j] * sc);
  }
}

// ---- k7: inverse along y ----
__global__ __launch_bounds__(256) void k_invy(const u16* __restrict__ o1, u16* __restrict__ o2,
                                              const float* __restrict__ Cf){
  int t = blockIdx.x * 256 + threadIdx.x;   // 147456
  int kz = t % 24; int xx = (t / 24) % 96; int o = t / 2304;
  const u16* in = o1 + (long)o * 55296 + xx * 576 + kz;
  float xin[24];
  #pragma unroll
  for (int ky = 0; ky < 24; ky++) xin[ky] = b2f(in[ky * 24]);
  u16* out = o2 + (long)o * 221184 + xx * 2304 + kz;
  const float sc = 1.f / 96.f;
  for (int y0 = 0; y0 < 96; y0 += 8){
    float acc[8];
    #pragma unroll
    for (int j = 0; j < 8; j++) acc[j] = 0.f;
    #pragma unroll
    for (int ky = 0; ky < 24; ky++){
      float f = xin[ky];
      const float* cf = Cf + ky * 96 + y0;
      #pragma unroll
      for (int j = 0; j < 8; j++) acc[j] = fmaf(f, cf[j], acc[j]);
    }
    #pragma unroll
    for (int j = 0; j < 8; j++) out[(y0 + j) * 24] = f2b(acc[j] * sc);
  }
}

// ---- k8: inverse along z -> u (bf16); gno stats ----
__global__ __launch_bounds__(256) void k_invz(const u16* __restrict__ o2, u16* __restrict__ u,
                                              const float* __restrict__ Cf, double* st){
  long r = (long)blockIdx.x * 256 + threadIdx.x;   // 589824 rows
  const u16* in = o2 + r * 24;
  us8 h0 = *(const us8*)(in), h1 = *(const us8*)(in + 8), h2 = *(const us8*)(in + 16);
  float xin[24];
  #pragma unroll
  for (int j = 0; j < 8; j++){ xin[j] = b2f(h0[j]); xin[8 + j] = b2f(h1[j]); xin[16 + j] = b2f(h2[j]); }
  u16* out = u + r * 96;
  float s = 0, q = 0;
  const float sc = 1.f / 96.f;
  for (int z0 = 0; z0 < 96; z0 += 8){
    float acc[8];
    #pragma unroll
    for (int j = 0; j < 8; j++) acc[j] = 0.f;
    #pragma unroll
    for (int kz = 0; kz < 24; kz++){
      float f = xin[kz];
      const float* cf = Cf + kz * 96 + z0;
      #pragma unroll
      for (int j = 0; j < 8; j++) acc[j] = fmaf(f, cf[j], acc[j]);
    }
    us8 o8;
    #pragma unroll
    for (int j = 0; j < 8; j++){
      float vv = acc[j] * sc;
      s += vv; q = fmaf(vv, vv, q);
      o8[j] = f2b(vv);
    }
    *(us8*)(out + z0) = o8;
  }
  statReduce(s, q, st + 6, st + 7);
}

// ---- k9: final concat-conv 128->64; LDS-tiled; gnc stats ----
// block = 64 voxels; stage normalized+relu'd [u;y] as bf16 in LDS (16 KB);
// thread = (voxel=lane, out-group=wave of 16 channels), acc[16].
template<int OBF> __device__ void fin_body(u16* xin, const u16* __restrict__ u,
    const u16* __restrict__ y, const float* __restrict__ W, void* __restrict__ zout,
    double* st){
  long vb = (long)blockIdx.x * 64;
  int t = threadIdx.x;
  float muo, rso, mum, rsm;
  get_mr(st, 6, NCH, muo, rso);
  get_mr(st, 0, NCH, mum, rsm);
  int row0 = t >> 3, seg = t & 7;   // 32 rows/pass x 8 thr x 8 elems; 4 passes
  #pragma unroll
  for (int p = 0; p < 4; p++){
    int row = row0 + 32 * p;
    const u16* src; float a, bb;
    if (row < 64){
      a = rso * W[10688 + row]; bb = W[10752 + row] - muo * a;
      src = u + (long)row * S3 + vb + seg * 8;
    } else {
      int rr = row - 64;
      a = rsm * W[2112 + rr]; bb = W[2176 + rr] - mum * a;
      src = y + (long)rr * S3 + vb + seg * 8;
    }
    us8 h = *(const us8*)src, o8;
    #pragma unroll
    for (int j = 0; j < 8; j++) o8[j] = f2b(fmaxf(fmaf(b2f(h[j]), a, bb), 0.f));
    *(us8*)&xin[row * 64 + seg * 8] = o8;
  }
  __syncthreads();
  int lane = t & 63, g = t >> 6;
  int ob = g * 16;
  float acc[16];
  #pragma unroll
  for (int o = 0; o < 16; o++) acc[o] = W[19008 + ob + o];
  for (int i = 0; i < 128; i++){
    float xi = b2f(xin[i * 64 + lane]);
    const float* wr = W + 10816 + i * 64 + ob;
    #pragma unroll
    for (int o = 0; o < 16; o++) acc[o] = fmaf(wr[o], xi, acc[o]);
  }
  float s = 0, q = 0;
  #pragma unroll
  for (int o = 0; o < 16; o++){
    s += acc[o]; q = fmaf(acc[o], acc[o], q);
    long oi = (long)(ob + o) * S3 + vb + lane;
    if (OBF) ((u16*)zout)[oi] = f2b(acc[o]);
    else     ((float*)zout)[oi] = acc[o];
  }
  statReduce(s, q, st + 8, st + 9);
}
__global__ __launch_bounds__(256) void k_fin(const u16* u, const u16* y, const float* W,
                                             void* z, double* st, const int* flag){
  __shared__ u16 xin[128 * 64];
  if (*flag) fin_body<1>(xin, u, y, W, z, st); else fin_body<0>(xin, u, y, W, z, st);
}

// ---- k10: GN_c + relu in-place on d_out ----
template<int OBF> __device__ void norm_body(void* z, const float* __restrict__ W,
                                            const double* __restrict__ st){
  long idx = ((long)blockIdx.x * 256 + threadIdx.x) * 8;
  float mu, rs; get_mr(st, 8, NCH, mu, rs);
  int c = (int)(idx / S3);
  float a = rs * W[19072 + c];
  float bb = W[19136 + c] - mu * a;
  if (OBF){
    u16* p = (u16*)z + idx;
    us8 h = *(us8*)p, o8;
    #pragma unroll
    for (int j = 0; j < 8; j++) o8[j] = f2b(fmaxf(fmaf(b2f(h[j]), a, bb), 0.f));
    *(us8*)p = o8;
  } else {
    float* p = (float*)z + idx;
    float4 v0 = *(float4*)p, v1 = *(float4*)(p + 4);
    v0.x = fmaxf(fmaf(v0.x, a, bb), 0.f); v0.y = fmaxf(fmaf(v0.y, a, bb), 0.f);
    v0.z = fmaxf(fmaf(v0.z, a, bb), 0.f); v0.w = fmaxf(fmaf(v0.w, a, bb), 0.f);
    v1.x = fmaxf(fmaf(v1.x, a, bb), 0.f); v1.y = fmaxf(fmaf(v1.y, a, bb), 0.f);
    v1.z = fmaxf(fmaf(v1.z, a, bb), 0.f); v1.w = fmaxf(fmaf(v1.w, a, bb), 0.f);
    *(float4*)p = v0; *(float4*)(p + 4) = v1;
  }
}
__global__ __launch_bounds__(256) void k_norm(void* z, const float* W, const double* st,
                                              const int* flag){
  if (*flag) norm_body<1>(z, W, st); else norm_body<0>(z, W, st);
}

extern "C" void kernel_launch(void* const* d_in, const int* in_sizes, int n_in,
                              void* d_out, int out_size, void* d_ws, size_t ws_size,
                              hipStream_t stream){
  char* ws = (char*)d_ws;
  float*  Cf   = (float*)(ws + A_CF);
  float*  Ct   = (float*)(ws + A_CT);
  double* st   = (double*)(ws + A_ST);
  int*    flag = (int*)(ws + A_FLAG);
  float*  W    = (float*)(ws + A_W);
  u16*    y    = (u16*)(ws + A_Y);
  u16*    t1   = (u16*)(ws + A_T1);
  u16*    t2   = (u16*)(ws + A_T2);
  float*  xc   = (float*)(ws + A_XC);
  float*  s0   = (float*)(ws + A_S0);
  float*  s1   = (float*)(ws + A_S1);
  u16*    u    = (u16*)(ws + A_U);

  k_init<<<1, 256, 0, stream>>>(Cf, Ct, st, flag, d_in[0]);

  Segs sg;
  const int offs[16] = {0,2048,2112,2176,2240,6336,6400,6464,10560,10624,10688,10752,10816,19008,19072,19136};
  const int ns[16]   = {2048,64,64,64,4096,64,64,4096,64,64,64,64,8192,64,64,64};
  const int idxs[16] = {1,2,3,4,6,7,8,10,11,12,13,14,15,16,17,18};
  for (int i = 0; i < 16; i++){ sg.src[i] = d_in[idxs[i]]; sg.n[i] = ns[i]; sg.off[i] = offs[i]; }
  k_conv<<<16, 256, 0, stream>>>(sg, W, flag);

  k_map <<<13824, 256, 0, stream>>>(d_in[0], W, y, st, flag);
  k_dhtz<<<2304, 256, 0, stream>>>(y, t1, Ct, W, st);
  k_dhty<<<576,  256, 0, stream>>>(t1, t2, Ct);
  k_dhtx<<<144,  256, 0, stream>>>(t2, xc, Ct);

  // spectral block 0: raw xc in; gn0 stats out
  k_spec<<<dim3(216, 16), 256, 0, stream>>>(xc, d_in[5], W, 2240, 0, -1, s0, st, 2, flag);
  // spectral block 1: normalize s0 with gn0; gn1 stats out
  k_spec<<<dim3(216, 16), 256, 0, stream>>>(s0, d_in[9], W, 6464, 6336, 2, s1, st, 4, flag);

  k_invx<<<144,  256, 0, stream>>>(s1, t2, Cf, W, st);   // t2 reused as o1
  k_invy<<<576,  256, 0, stream>>>(t2, t1, Cf);          // t1 reused as o2
  k_invz<<<2304, 256, 0, stream>>>(t1, u, Cf, st);

  k_fin <<<13824, 256, 0, stream>>>(u, y, W, d_out, st, flag);
  k_norm<<<27648, 256, 0, stream>>>(d_out, W, st, flag);
}

// Round 3
// 1776.399 us; speedup vs baseline: 1.3492x; 1.2762x over previous
//
#include <hip/hip_runtime.h>
#include <math.h>

typedef unsigned short u16;
typedef unsigned short us8 __attribute__((ext_vector_type(8)));

#define S3 884736L
#define MD3 13824L
#define NCH 56623104.0
#define NSP 884736.0

// ---- workspace layout (bytes) ----
#define A_CF   0L          // float Cf[24*96]   basis [k][n]
#define A_CT   9216L       // float Ct[96*24]   basis [n][k] (transposed)
#define A_ST   18432L      // double stats[16]: 0,1=gnm 2,3=gn0 4,5=gn1 6,7=gno 8,9=gnc
#define A_FLAG 18560L      // int: 1 = inputs are bf16, 0 = f32
#define A_W    18688L      // float[19200] converted small weights
#define A_Y    95488L      // bf16 y   [64][96^3]   mapping output (pre-GN)
#define A_T1   113341696L  // bf16 t1  [64][96][96][24]  (reused as o2)
#define A_T2   141653248L  // bf16 t2  [64][96][24][24]  (reused as o1)
#define A_XC   148731136L  // f32 xc   [64][24^3]
#define A_S0   152270080L  // f32 s0   [64][24^3]
#define A_S1   155809024L  // f32 s1   [64][24^3]
#define A_U    159347968L  // bf16 u   [64][96^3]   idht output (pre-GN)
// total = 272,594,176 bytes

// W layout (floats): Wm@0(2048) bm@2048 gnm_w@2112 gnm_b@2176 cw0@2240(4096)
// gn0_w@6336 gn0_b@6400 cw1@6464(4096) gn1_w@10560 gn1_b@10624 gno_w@10688
// gno_b@10752 Wc@10816(8192) bc@19008 gnc_w@19072 gnc_b@19136

__device__ __forceinline__ float b2f(u16 h){
  unsigned int u = ((unsigned int)h) << 16; float f;
  __builtin_memcpy(&f, &u, 4); return f;
}
__device__ __forceinline__ u16 f2b(float x){
  unsigned int u; __builtin_memcpy(&u, &x, 4);
  u = (u + 0x7FFFu + ((u >> 16) & 1u)) >> 16;
  return (u16)u;
}
template<int BF> __device__ __forceinline__ float ldin(const void* p, long i){
  return BF ? b2f(((const u16*)p)[i]) : ((const float*)p)[i];
}
__device__ __forceinline__ void get_mr(const double* st, int idx, double cnt,
                                       float& mu, float& rs){
  double m = st[idx] / cnt;
  double v = st[idx + 1] / cnt - m * m;
  mu = (float)m;
  rs = (float)(1.0 / sqrt(v + 1e-5));
}
// block = 256 threads (4 waves) assumed
__device__ __forceinline__ void statReduce(float s, float q, double* d0, double* d1){
  #pragma unroll
  for (int off = 32; off > 0; off >>= 1){
    s += __shfl_down(s, off, 64);
    q += __shfl_down(q, off, 64);
  }
  __shared__ float red[8];
  int w = threadIdx.x >> 6;
  if ((threadIdx.x & 63) == 0){ red[w] = s; red[4 + w] = q; }
  __syncthreads();
  if (threadIdx.x == 0){
    atomicAdd(d0, (double)(red[0] + red[1] + red[2] + red[3]));
    atomicAdd(d1, (double)(red[4] + red[5] + red[6] + red[7]));
  }
}

// ---- k0a: zero stats, detect dtype, build cas basis tables ----
__global__ __launch_bounds__(256) void k_init(float* Cf, float* Ct, double* st,
                                              int* flag, const void* x){
  int t = threadIdx.x;
  if (t < 16) st[t] = 0.0;
  if (t == 0){
    const u16* u = (const u16*)x; int sane = 0;
    for (int i = 0; i < 256; i++){
      int ex = (u[i] >> 7) & 0xFF;
      if (ex == 0 || (ex >= 104 && ex <= 150)) sane++;
    }
    *flag = (sane >= 240) ? 1 : 0;
  }
  for (int i = t; i < 2304; i += 256){
    int kk = i / 96, n = i - kk * 96;
    int k = kk < 12 ? kk : kk + 72;   // kept freqs {0..11, 84..95}
    int r = (k * n) % 96;
    double th = 6.283185307179586 * (double)r / 96.0;
    float v = (float)(cos(th) + sin(th));   // cas
    Cf[kk * 96 + n] = v;
    Ct[n * 24 + kk] = v;
  }
}

// ---- k0b: convert small weights to f32 in ws ----
struct Segs { const void* src[16]; int n[16]; int off[16]; };
__global__ __launch_bounds__(256) void k_conv(Segs sg, float* W, const int* flag){
  int b = blockIdx.x;
  int bf = *flag;
  const void* s = sg.src[b]; int n = sg.n[b]; float* d = W + sg.off[b];
  for (int i = threadIdx.x; i < n; i += blockDim.x)
    d[i] = bf ? b2f(((const u16*)s)[i]) : ((const float*)s)[i];
}

// ---- k1: mapping conv 32->64 + bias; LDS-tiled; store bf16 y; gnm stats ----
// block = 64 voxels; thread = (voxel=lane, out-group=wave of 16 channels)
// g is readfirstlane'd so weight addresses are SGPR-uniform -> s_load, no VMEM
template<int BF> __device__ void map_body(float* xs, const void* x,
                                          const float* __restrict__ W,
                                          u16* __restrict__ y, double* st){
  long vb = (long)blockIdx.x * 64;
  int t = threadIdx.x;
  if (BF){
    int row = t >> 3, seg = t & 7;              // 32 rows x 8 threads x 8 elems
    const u16* src = (const u16*)x + (long)row * S3 + vb + seg * 8;
    us8 h = *(const us8*)src;
    #pragma unroll
    for (int j = 0; j < 8; j++) xs[row * 64 + seg * 8 + j] = b2f(h[j]);
  } else {
    int row = t >> 4, seg = t & 15;             // 16 rows/pass x 16 thr x 4 f32
    #pragma unroll
    for (int p = 0; p < 2; p++){
      const float* src = (const float*)x + (long)(row + 16 * p) * S3 + vb + seg * 4;
      float4 v4 = *(const float4*)src;
      *(float4*)&xs[(row + 16 * p) * 64 + seg * 4] = v4;
    }
  }
  __syncthreads();
  int lane = t & 63;
  int g = __builtin_amdgcn_readfirstlane(t >> 6);   // wave-uniform in SGPR
  int ob = g * 16;
  float acc[16];
  #pragma unroll
  for (int o = 0; o < 16; o++) acc[o] = W[2048 + ob + o];
  for (int i = 0; i < 32; i++){
    float xi = xs[i * 64 + lane];
    const float* wr = W + i * 64 + ob;
    #pragma unroll
    for (int o = 0; o < 16; o++) acc[o] = fmaf(wr[o], xi, acc[o]);
  }
  float s = 0, q = 0;
  #pragma unroll
  for (int o = 0; o < 16; o++){
    s += acc[o]; q = fmaf(acc[o], acc[o], q);
    y[(long)(ob + o) * S3 + vb + lane] = f2b(acc[o]);
  }
  statReduce(s, q, st, st + 1);
}
__global__ __launch_bounds__(256) void k_map(const void* x, const float* W, u16* y,
                                             double* st, const int* flag){
  __shared__ float xs[32 * 64];
  if (*flag) map_body<1>(xs, x, W, y, st); else map_body<0>(xs, x, W, y, st);
}

// ---- k2: GN_m + relu on the fly, DHT along z (96 -> 24 modes) ----
__global__ __launch_bounds__(256) void k_dhtz(const u16* __restrict__ y, u16* __restrict__ t1,
                                              const float* __restrict__ Ct,
                                              const float* __restrict__ W,
                                              const double* __restrict__ st){
  long r = (long)blockIdx.x * 256 + threadIdx.x;   // (c,x,y) row, 589824
  int c = (int)(r / 9216);
  float mu, rs; get_mr(st, 0, NCH, mu, rs);
  float a = rs * W[2112 + c];
  float bb = W[2176 + c] - mu * a;
  const u16* in = y + r * 96;
  float acc[24];
  #pragma unroll
  for (int k = 0; k < 24; k++) acc[k] = 0.f;
  for (int z0 = 0; z0 < 96; z0 += 8){
    us8 h = *(const us8*)(in + z0);
    #pragma unroll
    for (int j = 0; j < 8; j++){
      float v = fmaxf(fmaf(b2f(h[j]), a, bb), 0.f);
      const float* ct = Ct + (z0 + j) * 24;
      #pragma unroll
      for (int k = 0; k < 24; k++) acc[k] = fmaf(v, ct[k], acc[k]);
    }
  }
  u16* out = t1 + r * 24;
  #pragma unroll
  for (int g = 0; g < 3; g++){
    us8 o8;
    #pragma unroll
    for (int j = 0; j < 8; j++) o8[j] = f2b(acc[g * 8 + j]);
    *(us8*)(out + g * 8) = o8;
  }
}

// ---- k3: DHT along y ----
__global__ __launch_bounds__(256) void k_dhty(const u16* __restrict__ t1, u16* __restrict__ t2,
                                              const float* __restrict__ Ct){
  int t = blockIdx.x * 256 + threadIdx.x;   // 147456 = (c,x) * kk
  int kk = t % 24; int cx = t / 24;
  const u16* in = t1 + (long)cx * 2304 + kk;
  float acc[24];
  #pragma unroll
  for (int k = 0; k < 24; k++) acc[k] = 0.f;
  for (int yy = 0; yy < 96; yy++){
    float v = b2f(in[yy * 24]);
    const float* ct = Ct + yy * 24;
    #pragma unroll
    for (int ky = 0; ky < 24; ky++) acc[ky] = fmaf(v, ct[ky], acc[ky]);
  }
  u16* out = t2 + (long)cx * 576 + kk;
  #pragma unroll
  for (int ky = 0; ky < 24; ky++) out[ky * 24] = f2b(acc[ky]);
}

// ---- k4: DHT along x -> xc (f32) ----
__global__ __launch_bounds__(256) void k_dhtx(const u16* __restrict__ t2, float* __restrict__ xc,
                                              const float* __restrict__ Ct){
  int t = blockIdx.x * 256 + threadIdx.x;   // 36864 = c * (ky,kz)
  int kykk = t % 576; int c = t / 576;
  const u16* in = t2 + (long)c * 55296 + kykk;
  float acc[24];
  #pragma unroll
  for (int k = 0; k < 24; k++) acc[k] = 0.f;
  for (int xx = 0; xx < 96; xx++){
    float v = b2f(in[xx * 576]);
    const float* ct = Ct + xx * 24;
    #pragma unroll
    for (int kx = 0; kx < 24; kx++) acc[kx] = fmaf(v, ct[kx], acc[kx]);
  }
  float* out = xc + (long)c * 13824 + kykk;
  #pragma unroll
  for (int kx = 0; kx < 24; kx++) out[kx * 576] = acc[kx];
}

// ---- k5: spectral block: x1(per-mode 64x64) + x2(1x1 conv) + residual; stats ----
template<int BF> __device__ void spec_body(float* xin, const float* __restrict__ in,
    const void* __restrict__ sw, const float* __restrict__ W, int cwOff, int gwOff,
    int statIn, float* __restrict__ out, double* st, int statOut){
  int lane = threadIdx.x & 63;
  int grp = __builtin_amdgcn_readfirstlane(threadIdx.x >> 6);  // SGPR-uniform
  long p = (long)blockIdx.x * 64 + lane;
  int o = blockIdx.y * 4 + grp;
  float mu = 0, rs = 0;
  if (statIn >= 0) get_mr(st, statIn, NSP, mu, rs);
  #pragma unroll
  for (int ii = 0; ii < 16; ii++){
    int i = grp + ii * 4;
    float v = in[i * MD3 + p];
    if (statIn >= 0){
      float a = rs * W[gwOff + i];
      v = fmaxf(fmaf(v, a, W[gwOff + 64 + i] - mu * a), 0.f);
    }
    xin[i * 64 + lane] = v;
  }
  __syncthreads();
  const float* cw = W + cwOff;
  float a1 = 0, a2 = 0;
  for (int i = 0; i < 64; i++){
    float xi = xin[i * 64 + lane];
    a1 = fmaf(ldin<BF>(sw, (long)(i * 64 + o) * MD3 + p), xi, a1);
    a2 = fmaf(cw[i * 64 + o], xi, a2);
  }
  float sv = a1 + a2 + xin[o * 64 + lane];
  out[o * MD3 + p] = sv;
  statReduce(sv, sv * sv, st + statOut, st + statOut + 1);
}
__global__ __launch_bounds__(256) void k_spec(const float* in, const void* sw, const float* W,
    int cwOff, int gwOff, int statIn, float* out, double* st, int statOut, const int* flag){
  __shared__ float xin[4096];
  if (*flag) spec_body<1>(xin, in, sw, W, cwOff, gwOff, statIn, out, st, statOut);
  else       spec_body<0>(xin, in, sw, W, cwOff, gwOff, statIn, out, st, statOut);
}

// ---- k6: GN1+relu on the fly, inverse along x (24 modes -> 96), scale 1/96 ----
__global__ __launch_bounds__(256) void k_invx(const float* __restrict__ s1, u16* __restrict__ o1,
                                              const float* __restrict__ Cf,
                                              const float* __restrict__ W,
                                              const double* __restrict__ st){
  int t = blockIdx.x * 256 + threadIdx.x;   // 36864
  int kykk = t % 576; int o = t / 576;
  float mu, rs; get_mr(st, 4, NSP, mu, rs);
  float a = rs * W[10560 + o];
  float bb = W[10624 + o] - mu * a;
  float xin[24];
  #pragma unroll
  for (int kx = 0; kx < 24; kx++)
    xin[kx] = fmaxf(fmaf(s1[(long)o * MD3 + kx * 576 + kykk], a, bb), 0.f);
  u16* out = o1 + (long)o * 55296 + kykk;
  const float sc = 1.f / 96.f;
  for (int x0 = 0; x0 < 96; x0 += 8){
    float acc[8];
    #pragma unroll
    for (int j = 0; j < 8; j++) acc[j] = 0.f;
    #pragma unroll
    for (int kx = 0; kx < 24; kx++){
      float f = xin[kx];
      const float* cf = Cf + kx * 96 + x0;
      #pragma unroll
      for (int j = 0; j < 8; j++) acc[j] = fmaf(f, cf[j], acc[j]);
    }
    #pragma unroll
    for (int j = 0; j < 8; j++) out[(x0 + j) * 576] = f2b(acc[j] * sc);
  }
}

// ---- k7: inverse along y ----
__global__ __launch_bounds__(256) void k_invy(const u16* __restrict__ o1, u16* __restrict__ o2,
                                              const float* __restrict__ Cf){
  int t = blockIdx.x * 256 + threadIdx.x;   // 147456
  int kz = t % 24; int xx = (t / 24) % 96; int o = t / 2304;
  const u16* in = o1 + (long)o * 55296 + xx * 576 + kz;
  float xin[24];
  #pragma unroll
  for (int ky = 0; ky < 24; ky++) xin[ky] = b2f(in[ky * 24]);
  u16* out = o2 + (long)o * 221184 + xx * 2304 + kz;
  const float sc = 1.f / 96.f;
  for (int y0 = 0; y0 < 96; y0 += 8){
    float acc[8];
    #pragma unroll
    for (int j = 0; j < 8; j++) acc[j] = 0.f;
    #pragma unroll
    for (int ky = 0; ky < 24; ky++){
      float f = xin[ky];
      const float* cf = Cf + ky * 96 + y0;
      #pragma unroll
      for (int j = 0; j < 8; j++) acc[j] = fmaf(f, cf[j], acc[j]);
    }
    #pragma unroll
    for (int j = 0; j < 8; j++) out[(y0 + j) * 24] = f2b(acc[j] * sc);
  }
}

// ---- k8: inverse along z -> u (bf16); gno stats ----
__global__ __launch_bounds__(256) void k_invz(const u16* __restrict__ o2, u16* __restrict__ u,
                                              const float* __restrict__ Cf, double* st){
  long r = (long)blockIdx.x * 256 + threadIdx.x;   // 589824 rows
  const u16* in = o2 + r * 24;
  us8 h0 = *(const us8*)(in), h1 = *(const us8*)(in + 8), h2 = *(const us8*)(in + 16);
  float xin[24];
  #pragma unroll
  for (int j = 0; j < 8; j++){ xin[j] = b2f(h0[j]); xin[8 + j] = b2f(h1[j]); xin[16 + j] = b2f(h2[j]); }
  u16* out = u + r * 96;
  float s = 0, q = 0;
  const float sc = 1.f / 96.f;
  for (int z0 = 0; z0 < 96; z0 += 8){
    float acc[8];
    #pragma unroll
    for (int j = 0; j < 8; j++) acc[j] = 0.f;
    #pragma unroll
    for (int kz = 0; kz < 24; kz++){
      float f = xin[kz];
      const float* cf = Cf + kz * 96 + z0;
      #pragma unroll
      for (int j = 0; j < 8; j++) acc[j] = fmaf(f, cf[j], acc[j]);
    }
    us8 o8;
    #pragma unroll
    for (int j = 0; j < 8; j++){
      float vv = acc[j] * sc;
      s += vv; q = fmaf(vv, vv, q);
      o8[j] = f2b(vv);
    }
    *(us8*)(out + z0) = o8;
  }
  statReduce(s, q, st + 6, st + 7);
}

// ---- k9: final concat-conv 128->64; LDS-tiled; gnc stats ----
// block = 64 voxels; stage normalized+relu'd [u;y] as bf16 in LDS (16 KB);
// thread = (voxel=lane, out-group=wave of 16 channels), acc[16].
// g readfirstlane'd -> weight rows via s_load, zero VMEM in inner loop.
template<int OBF> __device__ void fin_body(u16* xin, const u16* __restrict__ u,
    const u16* __restrict__ y, const float* __restrict__ W, void* __restrict__ zout,
    double* st){
  long vb = (long)blockIdx.x * 64;
  int t = threadIdx.x;
  float muo, rso, mum, rsm;
  get_mr(st, 6, NCH, muo, rso);
  get_mr(st, 0, NCH, mum, rsm);
  int row0 = t >> 3, seg = t & 7;   // 32 rows/pass x 8 thr x 8 elems; 4 passes
  #pragma unroll
  for (int p = 0; p < 4; p++){
    int row = row0 + 32 * p;
    const u16* src; float a, bb;
    if (row < 64){
      a = rso * W[10688 + row]; bb = W[10752 + row] - muo * a;
      src = u + (long)row * S3 + vb + seg * 8;
    } else {
      int rr = row - 64;
      a = rsm * W[2112 + rr]; bb = W[2176 + rr] - mum * a;
      src = y + (long)rr * S3 + vb + seg * 8;
    }
    us8 h = *(const us8*)src, o8;
    #pragma unroll
    for (int j = 0; j < 8; j++) o8[j] = f2b(fmaxf(fmaf(b2f(h[j]), a, bb), 0.f));
    *(us8*)&xin[row * 64 + seg * 8] = o8;
  }
  __syncthreads();
  int lane = t & 63;
  int g = __builtin_amdgcn_readfirstlane(t >> 6);   // wave-uniform in SGPR
  int ob = g * 16;
  float acc[16];
  #pragma unroll
  for (int o = 0; o < 16; o++) acc[o] = W[19008 + ob + o];
  for (int i = 0; i < 128; i++){
    float xi = b2f(xin[i * 64 + lane]);
    const float* wr = W + 10816 + i * 64 + ob;
    #pragma unroll
    for (int o = 0; o < 16; o++) acc[o] = fmaf(wr[o], xi, acc[o]);
  }
  float s = 0, q = 0;
  #pragma unroll
  for (int o = 0; o < 16; o++){
    s += acc[o]; q = fmaf(acc[o], acc[o], q);
    long oi = (long)(ob + o) * S3 + vb + lane;
    if (OBF) ((u16*)zout)[oi] = f2b(acc[o]);
    else     ((float*)zout)[oi] = acc[o];
  }
  statReduce(s, q, st + 8, st + 9);
}
__global__ __launch_bounds__(256) void k_fin(const u16* u, const u16* y, const float* W,
                                             void* z, double* st, const int* flag){
  __shared__ u16 xin[128 * 64];
  if (*flag) fin_body<1>(xin, u, y, W, z, st); else fin_body<0>(xin, u, y, W, z, st);
}

// ---- k10: GN_c + relu in-place on d_out ----
template<int OBF> __device__ void norm_body(void* z, const float* __restrict__ W,
                                            const double* __restrict__ st){
  long idx = ((long)blockIdx.x * 256 + threadIdx.x) * 8;
  float mu, rs; get_mr(st, 8, NCH, mu, rs);
  int c = (int)(idx / S3);
  float a = rs * W[19072 + c];
  float bb = W[19136 + c] - mu * a;
  if (OBF){
    u16* p = (u16*)z + idx;
    us8 h = *(us8*)p, o8;
    #pragma unroll
    for (int j = 0; j < 8; j++) o8[j] = f2b(fmaxf(fmaf(b2f(h[j]), a, bb), 0.f));
    *(us8*)p = o8;
  } else {
    float* p = (float*)z + idx;
    float4 v0 = *(float4*)p, v1 = *(float4*)(p + 4);
    v0.x = fmaxf(fmaf(v0.x, a, bb), 0.f); v0.y = fmaxf(fmaf(v0.y, a, bb), 0.f);
    v0.z = fmaxf(fmaf(v0.z, a, bb), 0.f); v0.w = fmaxf(fmaf(v0.w, a, bb), 0.f);
    v1.x = fmaxf(fmaf(v1.x, a, bb), 0.f); v1.y = fmaxf(fmaf(v1.y, a, bb), 0.f);
    v1.z = fmaxf(fmaf(v1.z, a, bb), 0.f); v1.w = fmaxf(fmaf(v1.w, a, bb), 0.f);
    *(float4*)p = v0; *(float4*)(p + 4) = v1;
  }
}
__global__ __launch_bounds__(256) void k_norm(void* z, const float* W, const double* st,
                                              const int* flag){
  if (*flag) norm_body<1>(z, W, st); else norm_body<0>(z, W, st);
}

extern "C" void kernel_launch(void* const* d_in, const int* in_sizes, int n_in,
                              void* d_out, int out_size, void* d_ws, size_t ws_size,
                              hipStream_t stream){
  char* ws = (char*)d_ws;
  float*  Cf   = (float*)(ws + A_CF);
  float*  Ct   = (float*)(ws + A_CT);
  double* st   = (double*)(ws + A_ST);
  int*    flag = (int*)(ws + A_FLAG);
  float*  W    = (float*)(ws + A_W);
  u16*    y    = (u16*)(ws + A_Y);
  u16*    t1   = (u16*)(ws + A_T1);
  u16*    t2   = (u16*)(ws + A_T2);
  float*  xc   = (float*)(ws + A_XC);
  float*  s0   = (float*)(ws + A_S0);
  float*  s1   = (float*)(ws + A_S1);
  u16*    u    = (u16*)(ws + A_U);

  k_init<<<1, 256, 0, stream>>>(Cf, Ct, st, flag, d_in[0]);

  Segs sg;
  const int offs[16] = {0,2048,2112,2176,2240,6336,6400,6464,10560,10624,10688,10752,10816,19008,19072,19136};
  const int ns[16]   = {2048,64,64,64,4096,64,64,4096,64,64,64,64,8192,64,64,64};
  const int idxs[16] = {1,2,3,4,6,7,8,10,11,12,13,14,15,16,17,18};
  for (int i = 0; i < 16; i++){ sg.src[i] = d_in[idxs[i]]; sg.n[i] = ns[i]; sg.off[i] = offs[i]; }
  k_conv<<<16, 256, 0, stream>>>(sg, W, flag);

  k_map <<<13824, 256, 0, stream>>>(d_in[0], W, y, st, flag);
  k_dhtz<<<2304, 256, 0, stream>>>(y, t1, Ct, W, st);
  k_dhty<<<576,  256, 0, stream>>>(t1, t2, Ct);
  k_dhtx<<<144,  256, 0, stream>>>(t2, xc, Ct);

  // spectral block 0: raw xc in; gn0 stats out
  k_spec<<<dim3(216, 16), 256, 0, stream>>>(xc, d_in[5], W, 2240, 0, -1, s0, st, 2, flag);
  // spectral block 1: normalize s0 with gn0; gn1 stats out
  k_spec<<<dim3(216, 16), 256, 0, stream>>>(s0, d_in[9], W, 6464, 6336, 2, s1, st, 4, flag);

  k_invx<<<144,  256, 0, stream>>>(s1, t2, Cf, W, st);   // t2 reused as o1
  k_invy<<<576,  256, 0, stream>>>(t2, t1, Cf);          // t1 reused as o2
  k_invz<<<2304, 256, 0, stream>>>(t1, u, Cf, st);

  k_fin <<<13824, 256, 0, stream>>>(u, y, W, d_out, st, flag);
  k_norm<<<27648, 256, 0, stream>>>(d_out, W, st, flag);
}